// Round 1
// baseline (2506.723 us; speedup 1.0000x reference)
//
#include <hip/hip_runtime.h>

#define NUM_PL 50000
#define NUM_TR 100000
#define NUM_AR 10000
#define NN     160000          // NUM_PL + NUM_TR + NUM_AR
#define HID    64
#define FEAT   128
#define E_PLTR 2000000
#define E_TRAR 100000
#define E_TOT  4200000         // 2*E_PLTR + 2*E_TRAR
#define OFF_TR 50000
#define OFF_AR 150000

// ---------------------------------------------------------------------------
// x[pl] = playlist_emb + type_emb[0];  x[ar] = artist_emb + type_emb[2]
// ---------------------------------------------------------------------------
__global__ __launch_bounds__(256) void k_init_emb(
    const float* __restrict__ pl_emb, const float* __restrict__ ar_emb,
    const float* __restrict__ type_emb, float* __restrict__ x) {
  int tid = blockIdx.x * 256 + threadIdx.x;
  int f = tid & (HID - 1);
  if (tid < NUM_PL * HID) {
    x[tid] = pl_emb[tid] + type_emb[f];
  } else {
    int idx = tid - NUM_PL * HID;
    if (idx < NUM_AR * HID)
      x[OFF_AR * HID + idx] = ar_emb[idx] + type_emb[2 * HID + f];
  }
}

// ---------------------------------------------------------------------------
// x[tr] = track_x @ W^T + b + type_emb[1]
// Block 256 = 4 waves; each wave: 8 rows, lane j = output feature.
// W staged k-major in LDS (lane-stride-1 -> 2-way bank alias, free).
// Row operands are wave-uniform addresses -> scalar loads.
// ---------------------------------------------------------------------------
__global__ __launch_bounds__(256) void k_track_lin(
    const float* __restrict__ tx, const float* __restrict__ W,
    const float* __restrict__ b, const float* __restrict__ type_emb,
    float* __restrict__ x) {
  __shared__ float WS[FEAT * HID];   // WS[k*64 + j] = W[j*128 + k]
  __shared__ float bs[HID];
  int t = threadIdx.x;
  for (int idx = t; idx < HID * FEAT; idx += 256) {
    int j = idx >> 7, k = idx & (FEAT - 1);
    WS[k * HID + j] = W[idx];
  }
  if (t < HID) bs[t] = b[t] + type_emb[HID + t];
  __syncthreads();

  int j  = t & 63;
  int wv = __builtin_amdgcn_readfirstlane(t >> 6);
  int row0 = blockIdx.x * 32 + wv * 8;
  const float* xr = tx + (size_t)row0 * FEAT;

  float acc[8] = {0.f, 0.f, 0.f, 0.f, 0.f, 0.f, 0.f, 0.f};
#pragma unroll 4
  for (int k = 0; k < FEAT; ++k) {
    float w = WS[k * HID + j];
#pragma unroll
    for (int r = 0; r < 8; ++r)
      acc[r] += xr[r * FEAT + k] * w;
  }
#pragma unroll
  for (int r = 0; r < 8; ++r)
    x[(OFF_TR + row0 + r) * HID + j] = acc[r] + bs[j];
}

// ---------------------------------------------------------------------------
// degrees: one thread per directed edge, +1.0 into deg[dst]
// ---------------------------------------------------------------------------
__global__ __launch_bounds__(256) void k_deg(
    const int* __restrict__ pls, const int* __restrict__ pld,
    const int* __restrict__ tas, const int* __restrict__ tad,
    float* __restrict__ deg) {
  int e = blockIdx.x * 256 + threadIdx.x;
  if (e >= E_TOT) return;
  int d;
  if (e < E_PLTR)                 d = pld[e] + OFF_TR;
  else if (e < 2 * E_PLTR)        d = pls[e - E_PLTR];
  else if (e < 2 * E_PLTR + E_TRAR) d = tad[e - 2 * E_PLTR] + OFF_AR;
  else                            d = tas[e - 2 * E_PLTR - E_TRAR] + OFF_TR;
  atomicAdd(&deg[d], 1.0f);
}

__global__ __launch_bounds__(256) void k_invdeg(float* __restrict__ deg) {
  int i = blockIdx.x * 256 + threadIdx.x;
  if (i < NN) deg[i] = 1.0f / fmaxf(deg[i], 1.0f);
}

// ---------------------------------------------------------------------------
// scatter: agg[dst] += x[src]; one wave per edge, lane = feature
// ---------------------------------------------------------------------------
__global__ __launch_bounds__(256) void k_scatter(
    const int* __restrict__ pls, const int* __restrict__ pld,
    const int* __restrict__ tas, const int* __restrict__ tad,
    const float* __restrict__ x, float* __restrict__ agg) {
  int tid = blockIdx.x * 256 + threadIdx.x;     // < 268.8M, fits int
  int e = tid >> 6;
  int f = tid & 63;
  int s, d;
  if (e < E_PLTR)                   { s = pls[e];               d = pld[e] + OFF_TR; }
  else if (e < 2 * E_PLTR)          { int i = e - E_PLTR;
                                      s = pld[i] + OFF_TR;      d = pls[i]; }
  else if (e < 2 * E_PLTR + E_TRAR) { int i = e - 2 * E_PLTR;
                                      s = tas[i] + OFF_TR;      d = tad[i] + OFF_AR; }
  else                              { int i = e - 2 * E_PLTR - E_TRAR;
                                      s = tad[i] + OFF_AR;      d = tas[i] + OFF_TR; }
  atomicAdd(&agg[d * HID + f], x[s * HID + f]);
}

// ---------------------------------------------------------------------------
// x = relu((agg*invdeg) @ Wl^T + bl + x @ Wr^T)   -- in place (each wave
// reads/writes only its own 8 rows, so no cross-thread hazard).
// ---------------------------------------------------------------------------
__global__ __launch_bounds__(256) void k_update(
    const float* __restrict__ agg, const float* __restrict__ invdeg,
    const float* __restrict__ Wl, const float* __restrict__ bl,
    const float* __restrict__ Wr, float* x) {
  __shared__ float WlS[HID * HID];   // [k][j]
  __shared__ float WrS[HID * HID];
  __shared__ float bs[HID];
  int t = threadIdx.x;
  for (int idx = t; idx < HID * HID; idx += 256) {
    int j = idx >> 6, k = idx & 63;
    WlS[k * HID + j] = Wl[idx];
    WrS[k * HID + j] = Wr[idx];
  }
  if (t < HID) bs[t] = bl[t];
  __syncthreads();

  int j  = t & 63;
  int wv = __builtin_amdgcn_readfirstlane(t >> 6);
  int n0 = blockIdx.x * 32 + wv * 8;
  const float* ar = agg + (size_t)n0 * HID;
  const float* xr = x + (size_t)n0 * HID;

  float accA[8] = {0.f, 0.f, 0.f, 0.f, 0.f, 0.f, 0.f, 0.f};
  float accX[8] = {0.f, 0.f, 0.f, 0.f, 0.f, 0.f, 0.f, 0.f};
#pragma unroll 4
  for (int k = 0; k < HID; ++k) {
    float wl = WlS[k * HID + j];
    float wr = WrS[k * HID + j];
#pragma unroll
    for (int r = 0; r < 8; ++r) {
      accA[r] += ar[r * HID + k] * wl;
      accX[r] += xr[r * HID + k] * wr;
    }
  }
#pragma unroll
  for (int r = 0; r < 8; ++r) {
    float v = accA[r] * invdeg[n0 + r] + accX[r] + bs[j];
    x[(n0 + r) * HID + j] = fmaxf(v, 0.f);
  }
}

// ---------------------------------------------------------------------------
extern "C" void kernel_launch(void* const* d_in, const int* in_sizes, int n_in,
                              void* d_out, int out_size, void* d_ws, size_t ws_size,
                              hipStream_t stream) {
  const float* track_x  = (const float*)d_in[0];
  const int*   pl_tr_s  = (const int*)d_in[1];
  const int*   pl_tr_d  = (const int*)d_in[2];
  const int*   tr_ar_s  = (const int*)d_in[3];
  const int*   tr_ar_d  = (const int*)d_in[4];
  const float* pl_emb   = (const float*)d_in[5];
  const float* ar_emb   = (const float*)d_in[6];
  const float* track_W  = (const float*)d_in[7];
  const float* track_b  = (const float*)d_in[8];
  const float* type_emb = (const float*)d_in[9];
  const float* conv_Wl  = (const float*)d_in[10];
  const float* conv_bl  = (const float*)d_in[11];
  const float* conv_Wr  = (const float*)d_in[12];

  float* x   = (float*)d_out;                 // node state lives in d_out (N*64)
  float* agg = (float*)d_ws;                  // N*64 floats
  float* deg = agg + (size_t)NN * HID;        // N floats (becomes invdeg)

  hipMemsetAsync(deg, 0, NN * sizeof(float), stream);

  k_init_emb<<<(NUM_PL + NUM_AR) * HID / 256, 256, 0, stream>>>(
      pl_emb, ar_emb, type_emb, x);
  k_track_lin<<<NUM_TR / 32, 256, 0, stream>>>(
      track_x, track_W, track_b, type_emb, x);
  k_deg<<<(E_TOT + 255) / 256, 256, 0, stream>>>(
      pl_tr_s, pl_tr_d, tr_ar_s, tr_ar_d, deg);
  k_invdeg<<<(NN + 255) / 256, 256, 0, stream>>>(deg);

  for (int l = 0; l < 2; ++l) {
    hipMemsetAsync(agg, 0, (size_t)NN * HID * sizeof(float), stream);
    k_scatter<<<E_TOT / 4, 256, 0, stream>>>(
        pl_tr_s, pl_tr_d, tr_ar_s, tr_ar_d, x, agg);
    k_update<<<NN / 32, 256, 0, stream>>>(
        agg, deg, conv_Wl + l * HID * HID, conv_bl + l * HID,
        conv_Wr + l * HID * HID, x);
  }
}

// Round 2
// 1247.317 us; speedup vs baseline: 2.0097x; 2.0097x over previous
//
#include <hip/hip_runtime.h>

#define NUM_PL 50000
#define NUM_TR 100000
#define NUM_AR 10000
#define NN     160000          // NUM_PL + NUM_TR + NUM_AR
#define HID    64
#define FEAT   128
#define E_PLTR 2000000
#define E_TRAR 100000
#define E_TOT  4200000         // 2*E_PLTR + 2*E_TRAR
#define OFF_TR 50000
#define OFF_AR 150000
#define NBLK_SCAN 625          // NN / 256

// edge id -> (src,dst) global node ids, matching the reference concatenation
__device__ __forceinline__ void edge_sd(
    int e, const int* __restrict__ pls, const int* __restrict__ pld,
    const int* __restrict__ tas, const int* __restrict__ tad, int& s, int& d) {
  if (e < E_PLTR)                   { s = pls[e];               d = pld[e] + OFF_TR; }
  else if (e < 2 * E_PLTR)          { int i = e - E_PLTR;
                                      s = pld[i] + OFF_TR;      d = pls[i]; }
  else if (e < 2 * E_PLTR + E_TRAR) { int i = e - 2 * E_PLTR;
                                      s = tas[i] + OFF_TR;      d = tad[i] + OFF_AR; }
  else                              { int i = e - 2 * E_PLTR - E_TRAR;
                                      s = tad[i] + OFF_AR;      d = tas[i] + OFF_TR; }
}

// ---------------------------------------------------------------------------
// x[pl] = playlist_emb + type_emb[0];  x[ar] = artist_emb + type_emb[2]
// ---------------------------------------------------------------------------
__global__ __launch_bounds__(256) void k_init_emb(
    const float* __restrict__ pl_emb, const float* __restrict__ ar_emb,
    const float* __restrict__ type_emb, float* __restrict__ x) {
  int tid = blockIdx.x * 256 + threadIdx.x;
  int f = tid & (HID - 1);
  if (tid < NUM_PL * HID) {
    x[tid] = pl_emb[tid] + type_emb[f];
  } else {
    int idx = tid - NUM_PL * HID;
    if (idx < NUM_AR * HID)
      x[OFF_AR * HID + idx] = ar_emb[idx] + type_emb[2 * HID + f];
  }
}

// ---------------------------------------------------------------------------
// x[tr] = track_x @ W^T + b + type_emb[1]   (wave: 8 rows, lane = out feat)
// ---------------------------------------------------------------------------
__global__ __launch_bounds__(256) void k_track_lin(
    const float* __restrict__ tx, const float* __restrict__ W,
    const float* __restrict__ b, const float* __restrict__ type_emb,
    float* __restrict__ x) {
  __shared__ float WS[FEAT * HID];   // WS[k*64 + j] = W[j*128 + k]
  __shared__ float bs[HID];
  int t = threadIdx.x;
  for (int idx = t; idx < HID * FEAT; idx += 256) {
    int j = idx >> 7, k = idx & (FEAT - 1);
    WS[k * HID + j] = W[idx];
  }
  if (t < HID) bs[t] = b[t] + type_emb[HID + t];
  __syncthreads();

  int j  = t & 63;
  int wv = __builtin_amdgcn_readfirstlane(t >> 6);
  int row0 = blockIdx.x * 32 + wv * 8;
  const float* xr = tx + (size_t)row0 * FEAT;

  float acc[8] = {0.f, 0.f, 0.f, 0.f, 0.f, 0.f, 0.f, 0.f};
#pragma unroll 4
  for (int k = 0; k < FEAT; ++k) {
    float w = WS[k * HID + j];
#pragma unroll
    for (int r = 0; r < 8; ++r)
      acc[r] += xr[r * FEAT + k] * w;
  }
#pragma unroll
  for (int r = 0; r < 8; ++r)
    x[(OFF_TR + row0 + r) * HID + j] = acc[r] + bs[j];
}

// ---------------------------------------------------------------------------
// CSR build: int degree count
// ---------------------------------------------------------------------------
__global__ __launch_bounds__(256) void k_deg_int(
    const int* __restrict__ pls, const int* __restrict__ pld,
    const int* __restrict__ tas, const int* __restrict__ tad,
    int* __restrict__ degi) {
  int e = blockIdx.x * 256 + threadIdx.x;
  if (e >= E_TOT) return;
  int s, d;
  edge_sd(e, pls, pld, tas, tad, s, d);
  atomicAdd(&degi[d], 1);
}

__global__ __launch_bounds__(256) void k_invdeg(
    const int* __restrict__ degi, float* __restrict__ invdeg) {
  int i = blockIdx.x * 256 + threadIdx.x;
  if (i < NN) invdeg[i] = 1.0f / (float)max(degi[i], 1);
}

// ---------------------------------------------------------------------------
// scan1: per-block (256) exclusive scan of degi -> rowptr, block total -> bsum
// ---------------------------------------------------------------------------
__global__ __launch_bounds__(256) void k_scan1(
    const int* __restrict__ degi, int* __restrict__ rowptr,
    int* __restrict__ bsum) {
  __shared__ int s[256];
  int t = threadIdx.x;
  int i = blockIdx.x * 256 + t;
  int val = degi[i];
  s[t] = val;
  __syncthreads();
  int incl = val;
#pragma unroll
  for (int off = 1; off < 256; off <<= 1) {
    int add = (t >= off) ? s[t - off] : 0;
    __syncthreads();
    incl += add;
    s[t] = incl;
    __syncthreads();
  }
  rowptr[i] = incl - val;               // exclusive within block
  if (t == 255) bsum[blockIdx.x] = incl;
}

// ---------------------------------------------------------------------------
// scan2: single block (1024 threads) exclusive scan of the 625 block sums
// ---------------------------------------------------------------------------
__global__ __launch_bounds__(1024) void k_scan2(int* __restrict__ bsum) {
  __shared__ int s[1024];
  int t = threadIdx.x;
  int val = (t < NBLK_SCAN) ? bsum[t] : 0;
  s[t] = val;
  __syncthreads();
  int incl = val;
#pragma unroll
  for (int off = 1; off < 1024; off <<= 1) {
    int add = (t >= off) ? s[t - off] : 0;
    __syncthreads();
    incl += add;
    s[t] = incl;
    __syncthreads();
  }
  if (t < NBLK_SCAN) bsum[t] = incl - val;  // exclusive
}

// ---------------------------------------------------------------------------
// scan3: rowptr[i] += bsum[block]; cursor[i] = rowptr[i]; rowptr[NN]=E_TOT
// ---------------------------------------------------------------------------
__global__ __launch_bounds__(256) void k_scan3(
    int* __restrict__ rowptr, const int* __restrict__ bsum,
    int* __restrict__ cursor) {
  int i = blockIdx.x * 256 + threadIdx.x;
  int v = rowptr[i] + bsum[blockIdx.x];
  rowptr[i] = v;
  cursor[i] = v;
  if (i == 0) rowptr[NN] = E_TOT;
}

// ---------------------------------------------------------------------------
// fill: col[cursor[d]++] = s
// ---------------------------------------------------------------------------
__global__ __launch_bounds__(256) void k_fill(
    const int* __restrict__ pls, const int* __restrict__ pld,
    const int* __restrict__ tas, const int* __restrict__ tad,
    int* __restrict__ cursor, int* __restrict__ col) {
  int e = blockIdx.x * 256 + threadIdx.x;
  if (e >= E_TOT) return;
  int s, d;
  edge_sd(e, pls, pld, tas, tad, s, d);
  int pos = atomicAdd(&cursor[d], 1);
  col[pos] = s;
}

// ---------------------------------------------------------------------------
// gather: agg[n] = mean over in-neighbors of x[src]
// one wave per node; lane = feature; col indices fetched 64-wide, broadcast
// ---------------------------------------------------------------------------
__global__ __launch_bounds__(256) void k_gather(
    const int* __restrict__ rowptr, const int* __restrict__ col,
    const float* __restrict__ invdeg, const float* __restrict__ x,
    float* __restrict__ agg) {
  int t = threadIdx.x;
  int lane = t & 63;
  int wv = __builtin_amdgcn_readfirstlane(t >> 6);
  int n = blockIdx.x * 4 + wv;
  int rp0 = rowptr[n], rp1 = rowptr[n + 1];

  float a0 = 0.f, a1 = 0.f, a2 = 0.f, a3 = 0.f;
  for (int base = rp0; base < rp1; base += 64) {
    int idx = base + lane;
    int cv = (idx < rp1) ? col[idx] : 0;
    int cnt = rp1 - base; if (cnt > 64) cnt = 64;
    int i = 0;
    for (; i + 4 <= cnt; i += 4) {
      int s0 = __shfl(cv, i);
      int s1 = __shfl(cv, i + 1);
      int s2 = __shfl(cv, i + 2);
      int s3 = __shfl(cv, i + 3);
      a0 += x[s0 * HID + lane];
      a1 += x[s1 * HID + lane];
      a2 += x[s2 * HID + lane];
      a3 += x[s3 * HID + lane];
    }
    for (; i < cnt; ++i) {
      int s0 = __shfl(cv, i);
      a0 += x[s0 * HID + lane];
    }
  }
  float sum = (a0 + a1) + (a2 + a3);
  agg[n * HID + lane] = sum * invdeg[n];
}

// ---------------------------------------------------------------------------
// x = relu(agg @ Wl^T + bl + x @ Wr^T)   (agg already mean'd); in-place x
// ---------------------------------------------------------------------------
__global__ __launch_bounds__(256) void k_update(
    const float* __restrict__ agg,
    const float* __restrict__ Wl, const float* __restrict__ bl,
    const float* __restrict__ Wr, float* x) {
  __shared__ float WlS[HID * HID];   // [k][j]
  __shared__ float WrS[HID * HID];
  __shared__ float bs[HID];
  int t = threadIdx.x;
  for (int idx = t; idx < HID * HID; idx += 256) {
    int j = idx >> 6, k = idx & 63;
    WlS[k * HID + j] = Wl[idx];
    WrS[k * HID + j] = Wr[idx];
  }
  if (t < HID) bs[t] = bl[t];
  __syncthreads();

  int j  = t & 63;
  int wv = __builtin_amdgcn_readfirstlane(t >> 6);
  int n0 = blockIdx.x * 32 + wv * 8;
  const float* ar = agg + (size_t)n0 * HID;
  const float* xr = x + (size_t)n0 * HID;

  float accA[8] = {0.f, 0.f, 0.f, 0.f, 0.f, 0.f, 0.f, 0.f};
  float accX[8] = {0.f, 0.f, 0.f, 0.f, 0.f, 0.f, 0.f, 0.f};
#pragma unroll 4
  for (int k = 0; k < HID; ++k) {
    float wl = WlS[k * HID + j];
    float wr = WrS[k * HID + j];
#pragma unroll
    for (int r = 0; r < 8; ++r) {
      accA[r] += ar[r * HID + k] * wl;
      accX[r] += xr[r * HID + k] * wr;
    }
  }
#pragma unroll
  for (int r = 0; r < 8; ++r) {
    float v = accA[r] + accX[r] + bs[j];
    x[(n0 + r) * HID + j] = fmaxf(v, 0.f);
  }
}

// ---------------------------------------------------------------------------
extern "C" void kernel_launch(void* const* d_in, const int* in_sizes, int n_in,
                              void* d_out, int out_size, void* d_ws, size_t ws_size,
                              hipStream_t stream) {
  const float* track_x  = (const float*)d_in[0];
  const int*   pl_tr_s  = (const int*)d_in[1];
  const int*   pl_tr_d  = (const int*)d_in[2];
  const int*   tr_ar_s  = (const int*)d_in[3];
  const int*   tr_ar_d  = (const int*)d_in[4];
  const float* pl_emb   = (const float*)d_in[5];
  const float* ar_emb   = (const float*)d_in[6];
  const float* track_W  = (const float*)d_in[7];
  const float* track_b  = (const float*)d_in[8];
  const float* type_emb = (const float*)d_in[9];
  const float* conv_Wl  = (const float*)d_in[10];
  const float* conv_bl  = (const float*)d_in[11];
  const float* conv_Wr  = (const float*)d_in[12];

  float* x = (float*)d_out;                      // node state (NN*64)

  // workspace layout (all 4-byte elements)
  char* w = (char*)d_ws;
  float* agg    = (float*)w;                     w += (size_t)NN * HID * 4;
  float* invdeg = (float*)w;                     w += (size_t)NN * 4;
  int*   degi   = (int*)w;                       w += (size_t)NN * 4;
  int*   rowptr = (int*)w;                       w += (size_t)(NN + 1) * 4;
  int*   cursor = (int*)w;                       w += (size_t)(NN + 1) * 4;
  int*   bsum   = (int*)w;                       w += (size_t)1024 * 4;
  int*   col    = (int*)w;                       // E_TOT ints

  hipMemsetAsync(degi, 0, NN * sizeof(int), stream);

  k_init_emb<<<(NUM_PL + NUM_AR) * HID / 256, 256, 0, stream>>>(
      pl_emb, ar_emb, type_emb, x);
  k_track_lin<<<NUM_TR / 32, 256, 0, stream>>>(
      track_x, track_W, track_b, type_emb, x);

  // CSR build
  k_deg_int<<<(E_TOT + 255) / 256, 256, 0, stream>>>(
      pl_tr_s, pl_tr_d, tr_ar_s, tr_ar_d, degi);
  k_invdeg<<<(NN + 255) / 256, 256, 0, stream>>>(degi, invdeg);
  k_scan1<<<NBLK_SCAN, 256, 0, stream>>>(degi, rowptr, bsum);
  k_scan2<<<1, 1024, 0, stream>>>(bsum);
  k_scan3<<<NBLK_SCAN, 256, 0, stream>>>(rowptr, bsum, cursor);
  k_fill<<<(E_TOT + 255) / 256, 256, 0, stream>>>(
      pl_tr_s, pl_tr_d, tr_ar_s, tr_ar_d, cursor, col);

  for (int l = 0; l < 2; ++l) {
    k_gather<<<NN / 4, 256, 0, stream>>>(rowptr, col, invdeg, x, agg);
    k_update<<<NN / 32, 256, 0, stream>>>(
        agg, conv_Wl + l * HID * HID, conv_bl + l * HID,
        conv_Wr + l * HID * HID, x);
  }
}

// Round 3
// 1089.671 us; speedup vs baseline: 2.3004x; 1.1447x over previous
//
#include <hip/hip_runtime.h>

#define NUM_PL 50000
#define NUM_TR 100000
#define NUM_AR 10000
#define NN     160000          // NUM_PL + NUM_TR + NUM_AR
#define HID    64
#define FEAT   128
#define E_PLTR 2000000
#define E_TRAR 100000
#define E_TOT  4200000         // 2*E_PLTR + 2*E_TRAR
#define OFF_TR 50000
#define OFF_AR 150000
#define NBLK_SCAN 625          // NN / 256
#define FILL_CHUNKS 2048
#define FILL_CHUNK_SZ ((E_TOT + FILL_CHUNKS - 1) / FILL_CHUNKS)   // 2051

// edge id -> (src,dst) global node ids, matching the reference concatenation
__device__ __forceinline__ void edge_sd(
    int e, const int* __restrict__ pls, const int* __restrict__ pld,
    const int* __restrict__ tas, const int* __restrict__ tad, int& s, int& d) {
  if (e < E_PLTR)                   { s = pls[e];               d = pld[e] + OFF_TR; }
  else if (e < 2 * E_PLTR)          { int i = e - E_PLTR;
                                      s = pld[i] + OFF_TR;      d = pls[i]; }
  else if (e < 2 * E_PLTR + E_TRAR) { int i = e - 2 * E_PLTR;
                                      s = tas[i] + OFF_TR;      d = tad[i] + OFF_AR; }
  else                              { int i = e - 2 * E_PLTR - E_TRAR;
                                      s = tad[i] + OFF_AR;      d = tas[i] + OFF_TR; }
}

// dst-range bucket, boundaries chosen to equalize edge counts (~525k each):
// pl (2M edges / 50k nodes) -> 4 buckets of 12.5k nodes
// tr (2.1M / 100k) + ar (0.1M / 10k) -> 4 buckets
__device__ __forceinline__ int dst_bucket(int d) {
  if (d < 50000) return d / 12500;
  if (d < 150000) return 4 + (d - 50000) / 25000;
  return 7;
}

// ---------------------------------------------------------------------------
// x[pl] = playlist_emb + type_emb[0];  x[ar] = artist_emb + type_emb[2]
// ---------------------------------------------------------------------------
__global__ __launch_bounds__(256) void k_init_emb(
    const float* __restrict__ pl_emb, const float* __restrict__ ar_emb,
    const float* __restrict__ type_emb, float* __restrict__ x) {
  int tid = blockIdx.x * 256 + threadIdx.x;
  int f = tid & (HID - 1);
  if (tid < NUM_PL * HID) {
    x[tid] = pl_emb[tid] + type_emb[f];
  } else {
    int idx = tid - NUM_PL * HID;
    if (idx < NUM_AR * HID)
      x[OFF_AR * HID + idx] = ar_emb[idx] + type_emb[2 * HID + f];
  }
}

// ---------------------------------------------------------------------------
// x[tr] = track_x @ W^T + b + type_emb[1]   (wave: 8 rows, lane = out feat)
// ---------------------------------------------------------------------------
__global__ __launch_bounds__(256) void k_track_lin(
    const float* __restrict__ tx, const float* __restrict__ W,
    const float* __restrict__ b, const float* __restrict__ type_emb,
    float* __restrict__ x) {
  __shared__ float WS[FEAT * HID];   // WS[k*64 + j] = W[j*128 + k]
  __shared__ float bs[HID];
  int t = threadIdx.x;
  for (int idx = t; idx < HID * FEAT; idx += 256) {
    int j = idx >> 7, k = idx & (FEAT - 1);
    WS[k * HID + j] = W[idx];
  }
  if (t < HID) bs[t] = b[t] + type_emb[HID + t];
  __syncthreads();

  int j  = t & 63;
  int wv = __builtin_amdgcn_readfirstlane(t >> 6);
  int row0 = blockIdx.x * 32 + wv * 8;
  const float* xr = tx + (size_t)row0 * FEAT;

  float acc[8] = {0.f, 0.f, 0.f, 0.f, 0.f, 0.f, 0.f, 0.f};
#pragma unroll 4
  for (int k = 0; k < FEAT; ++k) {
    float w = WS[k * HID + j];
#pragma unroll
    for (int r = 0; r < 8; ++r)
      acc[r] += xr[r * FEAT + k] * w;
  }
#pragma unroll
  for (int r = 0; r < 8; ++r)
    x[(OFF_TR + row0 + r) * HID + j] = acc[r] + bs[j];
}

// ---------------------------------------------------------------------------
// CSR build: int degree count
// ---------------------------------------------------------------------------
__global__ __launch_bounds__(256) void k_deg_int(
    const int* __restrict__ pls, const int* __restrict__ pld,
    const int* __restrict__ tas, const int* __restrict__ tad,
    int* __restrict__ degi) {
  int e = blockIdx.x * 256 + threadIdx.x;
  if (e >= E_TOT) return;
  int s, d;
  edge_sd(e, pls, pld, tas, tad, s, d);
  atomicAdd(&degi[d], 1);
}

__global__ __launch_bounds__(256) void k_invdeg(
    const int* __restrict__ degi, float* __restrict__ invdeg) {
  int i = blockIdx.x * 256 + threadIdx.x;
  if (i < NN) invdeg[i] = 1.0f / (float)max(degi[i], 1);
}

// ---------------------------------------------------------------------------
// scan1: per-block (256) exclusive scan of degi -> rowptr, block total -> bsum
// ---------------------------------------------------------------------------
__global__ __launch_bounds__(256) void k_scan1(
    const int* __restrict__ degi, int* __restrict__ rowptr,
    int* __restrict__ bsum) {
  __shared__ int s[256];
  int t = threadIdx.x;
  int i = blockIdx.x * 256 + t;
  int val = degi[i];
  s[t] = val;
  __syncthreads();
  int incl = val;
#pragma unroll
  for (int off = 1; off < 256; off <<= 1) {
    int add = (t >= off) ? s[t - off] : 0;
    __syncthreads();
    incl += add;
    s[t] = incl;
    __syncthreads();
  }
  rowptr[i] = incl - val;               // exclusive within block
  if (t == 255) bsum[blockIdx.x] = incl;
}

// ---------------------------------------------------------------------------
// scan2: single block (1024 threads) exclusive scan of the 625 block sums
// ---------------------------------------------------------------------------
__global__ __launch_bounds__(1024) void k_scan2(int* __restrict__ bsum) {
  __shared__ int s[1024];
  int t = threadIdx.x;
  int val = (t < NBLK_SCAN) ? bsum[t] : 0;
  s[t] = val;
  __syncthreads();
  int incl = val;
#pragma unroll
  for (int off = 1; off < 1024; off <<= 1) {
    int add = (t >= off) ? s[t - off] : 0;
    __syncthreads();
    incl += add;
    s[t] = incl;
    __syncthreads();
  }
  if (t < NBLK_SCAN) bsum[t] = incl - val;  // exclusive
}

// ---------------------------------------------------------------------------
// scan3: rowptr[i] += bsum[block]; cursor[i] = rowptr[i]; rowptr[NN]=E_TOT
// ---------------------------------------------------------------------------
__global__ __launch_bounds__(256) void k_scan3(
    int* __restrict__ rowptr, const int* __restrict__ bsum,
    int* __restrict__ cursor) {
  int i = blockIdx.x * 256 + threadIdx.x;
  int v = rowptr[i] + bsum[blockIdx.x];
  rowptr[i] = v;
  cursor[i] = v;
  if (i == 0) rowptr[NN] = E_TOT;
}

// ---------------------------------------------------------------------------
// fill: col[cursor[d]++] = s, bucketed by dst range so each XCD (blockIdx&7
// under round-robin dispatch) writes a ~2MB col window that fits its L2.
// Correct regardless of the actual block->XCD mapping (all bucket x chunk
// pairs are processed).
// ---------------------------------------------------------------------------
__global__ __launch_bounds__(256) void k_fill(
    const int* __restrict__ pls, const int* __restrict__ pld,
    const int* __restrict__ tas, const int* __restrict__ tad,
    int* __restrict__ cursor, int* __restrict__ col) {
  int bucket = blockIdx.x & 7;
  int chunk  = blockIdx.x >> 3;
  int e0 = chunk * FILL_CHUNK_SZ;
  int e1 = e0 + FILL_CHUNK_SZ;
  if (e1 > E_TOT) e1 = E_TOT;
  for (int e = e0 + threadIdx.x; e < e1; e += 256) {
    int s, d;
    edge_sd(e, pls, pld, tas, tad, s, d);
    if (dst_bucket(d) == bucket) {
      int pos = atomicAdd(&cursor[d], 1);
      col[pos] = s;
    }
  }
}

// ---------------------------------------------------------------------------
// gather: agg[n] = invdeg[n] * sum over in-neighbors of x[src]
// one wave per node; lane = (neighbor slot r = lane>>4, float4 col c=lane&15)
// -> each global_load_dwordx4 fetches 4 random 256B rows; xor-shuffle reduce.
// ---------------------------------------------------------------------------
__global__ __launch_bounds__(256) void k_gather(
    const int* __restrict__ rowptr, const int* __restrict__ col,
    const float* __restrict__ invdeg, const float* __restrict__ x,
    float* __restrict__ agg) {
  int t = threadIdx.x;
  int lane = t & 63;
  int wv = t >> 6;
  int n = blockIdx.x * 4 + wv;
  int rp0 = rowptr[n], rp1 = rowptr[n + 1];
  int r = lane >> 4;          // neighbor slot 0..3
  int c = lane & 15;          // float4 column 0..15
  const float4* x4 = (const float4*)x;

  float4 a0 = {0.f, 0.f, 0.f, 0.f};
  float4 a1 = {0.f, 0.f, 0.f, 0.f};
  int base = rp0;
  for (; base + 8 <= rp1; base += 8) {
    int s0 = col[base + r];
    int s1 = col[base + 4 + r];
    float4 v0 = x4[(size_t)s0 * 16 + c];
    float4 v1 = x4[(size_t)s1 * 16 + c];
    a0.x += v0.x; a0.y += v0.y; a0.z += v0.z; a0.w += v0.w;
    a1.x += v1.x; a1.y += v1.y; a1.z += v1.z; a1.w += v1.w;
  }
  if (base + 4 <= rp1) {
    int s0 = col[base + r];
    float4 v0 = x4[(size_t)s0 * 16 + c];
    a0.x += v0.x; a0.y += v0.y; a0.z += v0.z; a0.w += v0.w;
    base += 4;
  }
  if (base + r < rp1) {
    int s1 = col[base + r];
    float4 v1 = x4[(size_t)s1 * 16 + c];
    a1.x += v1.x; a1.y += v1.y; a1.z += v1.z; a1.w += v1.w;
  }
  float4 a;
  a.x = a0.x + a1.x; a.y = a0.y + a1.y; a.z = a0.z + a1.z; a.w = a0.w + a1.w;
  // reduce across the 4 neighbor-slot groups (xor 16, then 32)
  a.x += __shfl_xor(a.x, 16); a.y += __shfl_xor(a.y, 16);
  a.z += __shfl_xor(a.z, 16); a.w += __shfl_xor(a.w, 16);
  a.x += __shfl_xor(a.x, 32); a.y += __shfl_xor(a.y, 32);
  a.z += __shfl_xor(a.z, 32); a.w += __shfl_xor(a.w, 32);
  if (r == 0) {
    float id = invdeg[n];
    float4 o;
    o.x = a.x * id; o.y = a.y * id; o.z = a.z * id; o.w = a.w * id;
    ((float4*)agg)[(size_t)n * 16 + c] = o;
  }
}

// ---------------------------------------------------------------------------
// x = relu(agg @ Wl^T + bl + x @ Wr^T)   (agg already mean'd); in-place x
// ---------------------------------------------------------------------------
__global__ __launch_bounds__(256) void k_update(
    const float* __restrict__ agg,
    const float* __restrict__ Wl, const float* __restrict__ bl,
    const float* __restrict__ Wr, float* x) {
  __shared__ float WlS[HID * HID];   // [k][j]
  __shared__ float WrS[HID * HID];
  __shared__ float bs[HID];
  int t = threadIdx.x;
  for (int idx = t; idx < HID * HID; idx += 256) {
    int j = idx >> 6, k = idx & 63;
    WlS[k * HID + j] = Wl[idx];
    WrS[k * HID + j] = Wr[idx];
  }
  if (t < HID) bs[t] = bl[t];
  __syncthreads();

  int j  = t & 63;
  int wv = __builtin_amdgcn_readfirstlane(t >> 6);
  int n0 = blockIdx.x * 32 + wv * 8;
  const float* ar = agg + (size_t)n0 * HID;
  const float* xr = x + (size_t)n0 * HID;

  float accA[8] = {0.f, 0.f, 0.f, 0.f, 0.f, 0.f, 0.f, 0.f};
  float accX[8] = {0.f, 0.f, 0.f, 0.f, 0.f, 0.f, 0.f, 0.f};
#pragma unroll 4
  for (int k = 0; k < HID; ++k) {
    float wl = WlS[k * HID + j];
    float wr = WrS[k * HID + j];
#pragma unroll
    for (int r = 0; r < 8; ++r) {
      accA[r] += ar[r * HID + k] * wl;
      accX[r] += xr[r * HID + k] * wr;
    }
  }
#pragma unroll
  for (int r = 0; r < 8; ++r) {
    float v = accA[r] + accX[r] + bs[j];
    x[(n0 + r) * HID + j] = fmaxf(v, 0.f);
  }
}

// ---------------------------------------------------------------------------
extern "C" void kernel_launch(void* const* d_in, const int* in_sizes, int n_in,
                              void* d_out, int out_size, void* d_ws, size_t ws_size,
                              hipStream_t stream) {
  const float* track_x  = (const float*)d_in[0];
  const int*   pl_tr_s  = (const int*)d_in[1];
  const int*   pl_tr_d  = (const int*)d_in[2];
  const int*   tr_ar_s  = (const int*)d_in[3];
  const int*   tr_ar_d  = (const int*)d_in[4];
  const float* pl_emb   = (const float*)d_in[5];
  const float* ar_emb   = (const float*)d_in[6];
  const float* track_W  = (const float*)d_in[7];
  const float* track_b  = (const float*)d_in[8];
  const float* type_emb = (const float*)d_in[9];
  const float* conv_Wl  = (const float*)d_in[10];
  const float* conv_bl  = (const float*)d_in[11];
  const float* conv_Wr  = (const float*)d_in[12];

  float* x = (float*)d_out;                      // node state (NN*64)

  // workspace layout (all 4-byte elements)
  char* w = (char*)d_ws;
  float* agg    = (float*)w;                     w += (size_t)NN * HID * 4;
  float* invdeg = (float*)w;                     w += (size_t)NN * 4;
  int*   degi   = (int*)w;                       w += (size_t)NN * 4;
  int*   rowptr = (int*)w;                       w += (size_t)(NN + 1) * 4;
  int*   cursor = (int*)w;                       w += (size_t)(NN + 1) * 4;
  int*   bsum   = (int*)w;                       w += (size_t)1024 * 4;
  int*   col    = (int*)w;                       // E_TOT ints

  hipMemsetAsync(degi, 0, NN * sizeof(int), stream);

  k_init_emb<<<(NUM_PL + NUM_AR) * HID / 256, 256, 0, stream>>>(
      pl_emb, ar_emb, type_emb, x);
  k_track_lin<<<NUM_TR / 32, 256, 0, stream>>>(
      track_x, track_W, track_b, type_emb, x);

  // CSR build
  k_deg_int<<<(E_TOT + 255) / 256, 256, 0, stream>>>(
      pl_tr_s, pl_tr_d, tr_ar_s, tr_ar_d, degi);
  k_invdeg<<<(NN + 255) / 256, 256, 0, stream>>>(degi, invdeg);
  k_scan1<<<NBLK_SCAN, 256, 0, stream>>>(degi, rowptr, bsum);
  k_scan2<<<1, 1024, 0, stream>>>(bsum);
  k_scan3<<<NBLK_SCAN, 256, 0, stream>>>(rowptr, bsum, cursor);
  k_fill<<<FILL_CHUNKS * 8, 256, 0, stream>>>(
      pl_tr_s, pl_tr_d, tr_ar_s, tr_ar_d, cursor, col);

  for (int l = 0; l < 2; ++l) {
    k_gather<<<NN / 4, 256, 0, stream>>>(rowptr, col, invdeg, x, agg);
    k_update<<<NN / 32, 256, 0, stream>>>(
        agg, conv_Wl + l * HID * HID, conv_bl + l * HID,
        conv_Wr + l * HID * HID, x);
  }
}